// Round 7
// baseline (120.063 us; speedup 1.0000x reference)
//
#include <hip/hip_runtime.h>

#define BB 16
#define CIN 256
#define COUT 128
#define EE 512
#define HH 64
#define WW 64
#define HP 66   // padded spatial dim

// ws layout (bytes):
//   bias1 [16][256] f32 @ 0        (16384)
//   bias2 [16][128] f32 @ 16384    (8192)
//   bias3 [16][128] f32 @ 24576    (8192)
//   A     [128] f32     @ 33280    (512)
//   B0    [128] f32     @ 33792    (512)
//   ctab  [128][8] i32  @ 34304    (4096)   {T,B,L,R,TL,TR,BL,BR} popc sums
//   wq    [4][128][9] u64 @ 38400  (36864)  (quarter-major, o, tap)
//   xq    [4][16][66][66] u64 @ 75264 (2230272)  zero-padded halo

// grid: 128 bias-chunk blocks (b*8+chunk) + 128 weight blocks.
__global__ __launch_bounds__(256) void prep_k(
    const float* __restrict__ emb,
    const float* __restrict__ m1w, const float* __restrict__ m1b,
    const float* __restrict__ m2w, const float* __restrict__ m2b,
    const float* __restrict__ m3w, const float* __restrict__ m3b,
    const float* __restrict__ conv_w, const float* __restrict__ conv_b,
    const float* __restrict__ bn_g, const float* __restrict__ bn_b,
    const float* __restrict__ bn_m, const float* __restrict__ bn_v,
    float* __restrict__ bias1, float* __restrict__ bias2, float* __restrict__ bias3,
    float* __restrict__ A, float* __restrict__ B0,
    int* __restrict__ ctab, unsigned long long* __restrict__ wq)
{
    int bid = blockIdx.x;
    int tid = threadIdx.x;
    __shared__ float red[256];
    if (bid < 128) {
        // bias dot-products: b = bid>>3, chunk = bid&7
        int b = bid >> 3;
        int chunk = bid & 7;
        __shared__ float se[EE];
        {
            float v0 = emb[b * EE + tid];
            float v1 = emb[b * EE + tid + 256];
            se[tid] = v0 / (1.0f + __expf(-v0));
            se[tid + 256] = v1 / (1.0f + __expf(-v1));
        }
        __syncthreads();
        int cl = tid & 63;
        int ks = tid >> 6;   // 0..3, each covers 128 e's
        const float* W;
        const float* Bv;
        float* dst;
        int c0;
        if (chunk < 4)      { c0 = chunk * 64;       W = m1w; Bv = m1b; dst = bias1 + b * CIN + c0; }
        else if (chunk < 6) { c0 = (chunk - 4) * 64; W = m2w; Bv = m2b; dst = bias2 + b * COUT + c0; }
        else                { c0 = (chunk - 6) * 64; W = m3w; Bv = m3b; dst = bias3 + b * COUT + c0; }
        const float4* w4 = (const float4*)(W + (size_t)(c0 + cl) * EE + ks * 128);
        const float* sp = &se[ks * 128];
        float acc = 0.f;
        #pragma unroll
        for (int e4 = 0; e4 < 32; ++e4) {
            float4 v = w4[e4];
            acc += sp[e4 * 4 + 0] * v.x + sp[e4 * 4 + 1] * v.y +
                   sp[e4 * 4 + 2] * v.z + sp[e4 * 4 + 3] * v.w;
        }
        red[tid] = acc;
        __syncthreads();
        if (ks == 0)
            dst[cl] = red[cl] + red[cl + 64] + red[cl + 128] + red[cl + 192] + Bv[c0 + cl];
    } else {
        int o = bid - 128;     // output channel
        int i = tid;           // input channel 0..255
        __shared__ int spc[36];
        float wv[9];
        float asum = 0.f;
        const float* wp = conv_w + ((size_t)o * CIN + i) * 9;
        #pragma unroll
        for (int k = 0; k < 9; ++k) {
            float v = wp[k];
            wv[k] = v;
            asum += fabsf(v);
        }
        int wave = tid >> 6;
        #pragma unroll
        for (int k = 0; k < 9; ++k) {
            unsigned long long m = __ballot(wv[k] > 0.0f);
            if ((tid & 63) == 0) {
                wq[((size_t)wave * COUT + o) * 9 + k] = m;
                spc[k * 4 + wave] = __popcll(m);
            }
        }
        red[tid] = asum;
        __syncthreads();
        for (int s = 128; s > 0; s >>= 1) {
            if (tid < s) red[tid] += red[tid + s];
            __syncthreads();
        }
        if (tid < 9)
            spc[tid] = spc[tid * 4 + 0] + spc[tid * 4 + 1] + spc[tid * 4 + 2] + spc[tid * 4 + 3];
        __syncthreads();
        if (tid == 0) {
            float sc = red[0] * (1.0f / 2304.0f);
            float inv = bn_g[o] * rsqrtf(bn_v[o] + 1e-5f);
            A[o] = sc * inv;
            B0[o] = (conv_b[o] - bn_m[o]) * inv + bn_b[o];
            int p0 = spc[0], p1 = spc[1], p2 = spc[2];
            int p3 = spc[3], p5 = spc[5];
            int p6 = spc[6], p7 = spc[7], p8 = spc[8];
            int* ct = ctab + o * 8;
            ct[0] = p0 + p1 + p2;   // T (row r=0 invalid)
            ct[1] = p6 + p7 + p8;   // B (row r=2 invalid)
            ct[2] = p0 + p3 + p6;   // L (col dw=0 invalid)
            ct[3] = p2 + p5 + p8;   // R (col dw=2 invalid)
            ct[4] = p0;             // TL corner
            ct[5] = p2;             // TR
            ct[6] = p6;             // BL
            ct[7] = p8;             // BR
        }
    }
}

// One block per (b,h) row. 256 threads = 64 w-lanes x 4 channel-quarters.
// Writes planar padded xq; also zeroes the halo ring (17 cells/block).
__global__ __launch_bounds__(256) void pack_k(
    const float* __restrict__ x, const float* __restrict__ bias1,
    unsigned long long* __restrict__ xq)
{
    int bid = blockIdx.x;          // b*64 + h
    int b = bid >> 6;
    int h = bid & 63;
    int tid = threadIdx.x;
    int w = tid & 63;
    int q = tid >> 6;              // channel quarter, wave-uniform

    // halo zeroing: 4*16*260 = 16640 halo cells, 17 per block
    int idx = bid * 17 + tid;
    if (tid < 17 && idx < 16640) {
        int qb = idx / 260;
        int c = idx % 260;
        int q2 = qb >> 4, b2 = qb & 15;
        int r, col;
        if (c < 66)       { r = 0;  col = c; }
        else if (c < 132) { r = 65; col = c - 66; }
        else              { int c2 = c - 132; r = 1 + (c2 >> 1); col = (c2 & 1) * 65; }
        xq[(((size_t)q2 * BB + b2) * HP + r) * HP + col] = 0ull;
    }

    __shared__ float sb[CIN];
    sb[tid] = bias1[b * CIN + tid];
    __syncthreads();
    const float* xp = x + ((size_t)b * CIN + (size_t)q * 64) * (HH * WW) + (size_t)h * WW + w;
    const float* bb = &sb[q * 64];
    unsigned long long m = 0;
    #pragma unroll
    for (int c = 0; c < 64; ++c) {
        if (xp[(size_t)c * (HH * WW)] + bb[c] > 0.f) m |= 1ull << c;
    }
    xq[(((size_t)q * BB + b) * HP + h + 1) * HP + (w + 1)] = m;
}

// 2048 blocks: bid = b*128 + h*2 + half. 256 threads = 64 w x 4 og-waves.
// 4 channel-quarter passes; per pass only 9 u64 live. Zero-padded halo
// means NO masks/clamps in the hot loop; exact border fixup via ctab.
__global__ __launch_bounds__(256, 4) void main_k(
    const unsigned long long* __restrict__ wq,     // [4][128][9]
    const unsigned long long* __restrict__ xq,     // [4][16][66][66]
    const int* __restrict__ ctab,                  // [128][8]
    const float* __restrict__ x,
    const float* __restrict__ A, const float* __restrict__ B0,
    const float* __restrict__ bias2, const float* __restrict__ bias3,
    const float* __restrict__ prelu_a,
    float* __restrict__ out)
{
    int bid = blockIdx.x;
    int half = bid & 1;
    int h = (bid >> 1) & 63;
    int b = bid >> 7;
    int tid = threadIdx.x;
    int w = tid & 63;
    int og = tid >> 6;
    int ou = __builtin_amdgcn_readfirstlane(half * 64 + og * 16);  // uniform o base

    int P[16];
    #pragma unroll
    for (int i = 0; i < 16; ++i) P[i] = 0;

    #pragma unroll
    for (int q = 0; q < 4; ++q) {
        // base points at padded (row=h, col=w) == tap (r=0,dw=0)
        const unsigned long long* xp =
            xq + (((size_t)(q * BB + b)) * HP + h) * HP + w;
        unsigned long long xv[9];
        xv[0] = xp[0];       xv[1] = xp[1];       xv[2] = xp[2];
        xv[3] = xp[HP];      xv[4] = xp[HP + 1];  xv[5] = xp[HP + 2];
        xv[6] = xp[2 * HP];  xv[7] = xp[2 * HP + 1]; xv[8] = xp[2 * HP + 2];
        const unsigned long long* wp = wq + ((size_t)q * COUT + ou) * 9;
        #pragma unroll
        for (int oo = 0; oo < 16; ++oo) {
            const unsigned long long* wo = wp + oo * 9;
            int s = 0;
            #pragma unroll
            for (int t = 0; t < 9; ++t)
                s += __popcll(xv[t] ^ wo[t]);
            P[oo] += s;
        }
    }

    int w0  = (w == 0)  ? -1 : 0;
    int w63 = (w == 63) ? -1 : 0;
    int cntc = 3 + w0 + w63;
    int rowsel = (h == 0) ? 0 : (h == 63) ? 1 : -1;  // block-uniform
    int cntr = (rowsel < 0) ? 3 : 2;
    int nv = cntr * cntc;

    #pragma unroll
    for (int oo = 0; oo < 16; ++oo) {
        int o = ou + oo;  // uniform
        const int* ct = ctab + o * 8;
        int corr = (w0 & ct[2]) + (w63 & ct[3]);
        if (rowsel == 0)      corr += ct[0] - ((w0 & ct[4]) + (w63 & ct[5]));
        else if (rowsel == 1) corr += ct[1] - ((w0 & ct[6]) + (w63 & ct[7]));
        int Peff = P[oo] - corr;
        float tv = (float)(nv * 256 - 2 * Peff) * A[o] + B0[o];
        float r0 = x[(((size_t)b * CIN + 2 * o) * HH + h) * WW + w];
        float r1 = x[(((size_t)b * CIN + 2 * o + 1) * HH + h) * WW + w];
        tv += 0.5f * (r0 + r1) + bias2[b * COUT + o];
        tv = tv > 0.f ? tv : prelu_a[o] * tv;
        out[(((size_t)b * COUT + o) * HH + h) * WW + w] = tv + bias3[b * COUT + o];
    }
}

extern "C" void kernel_launch(void* const* d_in, const int* in_sizes, int n_in,
                              void* d_out, int out_size, void* d_ws, size_t ws_size,
                              hipStream_t stream) {
    const float* x      = (const float*)d_in[0];
    const float* emb    = (const float*)d_in[1];
    const float* m1w    = (const float*)d_in[2];
    const float* m1b    = (const float*)d_in[3];
    const float* conv_w = (const float*)d_in[4];
    const float* conv_b = (const float*)d_in[5];
    const float* bn_g   = (const float*)d_in[6];
    const float* bn_b   = (const float*)d_in[7];
    const float* bn_m   = (const float*)d_in[8];
    const float* bn_v   = (const float*)d_in[9];
    const float* m2w    = (const float*)d_in[10];
    const float* m2b    = (const float*)d_in[11];
    const float* pa     = (const float*)d_in[12];
    const float* m3w    = (const float*)d_in[13];
    const float* m3b    = (const float*)d_in[14];
    float* out = (float*)d_out;

    char* ws = (char*)d_ws;
    float* bias1 = (float*)(ws + 0);
    float* bias2 = (float*)(ws + 16384);
    float* bias3 = (float*)(ws + 24576);
    float* Aarr  = (float*)(ws + 33280);
    float* B0arr = (float*)(ws + 33792);
    int*   ctab  = (int*)(ws + 34304);
    unsigned long long* wq = (unsigned long long*)(ws + 38400);
    unsigned long long* xq = (unsigned long long*)(ws + 75264);

    prep_k<<<256, 256, 0, stream>>>(emb, m1w, m1b, m2w, m2b, m3w, m3b,
                                    conv_w, conv_b, bn_g, bn_b, bn_m, bn_v,
                                    bias1, bias2, bias3, Aarr, B0arr, ctab, wq);
    pack_k<<<BB * HH, 256, 0, stream>>>(x, bias1, xq);
    main_k<<<BB * HH * 2, 256, 0, stream>>>(wq, xq, ctab, x, Aarr, B0arr,
                                            bias2, bias3, pa, out);
}

// Round 8
// 94.260 us; speedup vs baseline: 1.2737x; 1.2737x over previous
//
#include <hip/hip_runtime.h>

#define BB 16
#define CIN 256
#define COUT 128
#define EE 512
#define HH 64
#define WW 64
#define HP 66   // padded spatial dim

// ws layout (bytes):
//   bias1 [16][256] f32 @ 0        (16384)
//   bias2 [16][128] f32 @ 16384    (8192)
//   bias3 [16][128] f32 @ 24576    (8192)
//   A     [128] f32     @ 33280    (512)
//   B0    [128] f32     @ 33792    (512)
//   ctab  [128][8] i32  @ 34304    (4096)   {T,B,L,R,TL,TR,BL,BR} popc sums
//   wpack [128][9][4] u64 @ 38400  (36864)  (o-major, tap, quarter)
//   xpack [16][66][66][4] u64 @ 75264 (2230272)  zero-padded halo

// grid: 128 bias-chunk blocks (b*8+chunk) + 128 weight blocks.
__global__ __launch_bounds__(256) void prep_k(
    const float* __restrict__ emb,
    const float* __restrict__ m1w, const float* __restrict__ m1b,
    const float* __restrict__ m2w, const float* __restrict__ m2b,
    const float* __restrict__ m3w, const float* __restrict__ m3b,
    const float* __restrict__ conv_w, const float* __restrict__ conv_b,
    const float* __restrict__ bn_g, const float* __restrict__ bn_b,
    const float* __restrict__ bn_m, const float* __restrict__ bn_v,
    float* __restrict__ bias1, float* __restrict__ bias2, float* __restrict__ bias3,
    float* __restrict__ A, float* __restrict__ B0,
    int* __restrict__ ctab, unsigned long long* __restrict__ wpack)
{
    int bid = blockIdx.x;
    int tid = threadIdx.x;
    __shared__ float red[256];
    if (bid < 128) {
        // bias dot-products: b = bid>>3, chunk = bid&7
        int b = bid >> 3;
        int chunk = bid & 7;
        __shared__ float se[EE];
        {
            float v0 = emb[b * EE + tid];
            float v1 = emb[b * EE + tid + 256];
            se[tid] = v0 / (1.0f + __expf(-v0));
            se[tid + 256] = v1 / (1.0f + __expf(-v1));
        }
        __syncthreads();
        int cl = tid & 63;
        int ks = tid >> 6;   // 0..3, each covers 128 e's
        const float* W;
        const float* Bv;
        float* dst;
        int c0;
        if (chunk < 4)      { c0 = chunk * 64;       W = m1w; Bv = m1b; dst = bias1 + b * CIN + c0; }
        else if (chunk < 6) { c0 = (chunk - 4) * 64; W = m2w; Bv = m2b; dst = bias2 + b * COUT + c0; }
        else                { c0 = (chunk - 6) * 64; W = m3w; Bv = m3b; dst = bias3 + b * COUT + c0; }
        const float4* w4 = (const float4*)(W + (size_t)(c0 + cl) * EE + ks * 128);
        const float* sp = &se[ks * 128];
        float acc = 0.f;
        #pragma unroll
        for (int e4 = 0; e4 < 32; ++e4) {
            float4 v = w4[e4];
            acc += sp[e4 * 4 + 0] * v.x + sp[e4 * 4 + 1] * v.y +
                   sp[e4 * 4 + 2] * v.z + sp[e4 * 4 + 3] * v.w;
        }
        red[tid] = acc;
        __syncthreads();
        if (ks == 0)
            dst[cl] = red[cl] + red[cl + 64] + red[cl + 128] + red[cl + 192] + Bv[c0 + cl];
    } else {
        int o = bid - 128;     // output channel
        int i = tid;           // input channel 0..255
        __shared__ int spc[36];
        float wv[9];
        float asum = 0.f;
        const float* wp = conv_w + ((size_t)o * CIN + i) * 9;
        #pragma unroll
        for (int k = 0; k < 9; ++k) {
            float v = wp[k];
            wv[k] = v;
            asum += fabsf(v);
        }
        int wave = tid >> 6;
        #pragma unroll
        for (int k = 0; k < 9; ++k) {
            unsigned long long m = __ballot(wv[k] > 0.0f);
            if ((tid & 63) == 0) {
                wpack[((size_t)o * 9 + k) * 4 + wave] = m;
                spc[k * 4 + wave] = __popcll(m);
            }
        }
        red[tid] = asum;
        __syncthreads();
        for (int s = 128; s > 0; s >>= 1) {
            if (tid < s) red[tid] += red[tid + s];
            __syncthreads();
        }
        if (tid < 9)
            spc[tid] = spc[tid * 4 + 0] + spc[tid * 4 + 1] + spc[tid * 4 + 2] + spc[tid * 4 + 3];
        __syncthreads();
        if (tid == 0) {
            float sc = red[0] * (1.0f / 2304.0f);
            float inv = bn_g[o] * rsqrtf(bn_v[o] + 1e-5f);
            A[o] = sc * inv;
            B0[o] = (conv_b[o] - bn_m[o]) * inv + bn_b[o];
            int p0 = spc[0], p1 = spc[1], p2 = spc[2];
            int p3 = spc[3], p5 = spc[5];
            int p6 = spc[6], p7 = spc[7], p8 = spc[8];
            int* ct = ctab + o * 8;
            ct[0] = p0 + p1 + p2;   // T (row r=0 invalid)
            ct[1] = p6 + p7 + p8;   // B (row r=2 invalid)
            ct[2] = p0 + p3 + p6;   // L (col dw=0 invalid)
            ct[3] = p2 + p5 + p8;   // R (col dw=2 invalid)
            ct[4] = p0;             // TL corner
            ct[5] = p2;             // TR
            ct[6] = p6;             // BL
            ct[7] = p8;             // BR
        }
    }
}

// One block per (b,h) row. 256 threads = 64 w-lanes x 4 channel-quarters.
// Writes padded xpack [16][66][66][4]; also zeroes the halo ring.
__global__ __launch_bounds__(256) void pack_k(
    const float* __restrict__ x, const float* __restrict__ bias1,
    unsigned long long* __restrict__ xq)
{
    int bid = blockIdx.x;          // b*64 + h
    int b = bid >> 6;
    int h = bid & 63;
    int tid = threadIdx.x;
    int w = tid & 63;
    int q = tid >> 6;              // channel quarter, wave-uniform

    // halo zeroing: 16 b * 260 ring-cells * 4 q = 16640 u64; 17 per block
    int idx = bid * 17 + tid;
    if (tid < 17 && idx < 16640) {
        int b2 = idx / 1040;
        int rem = idx % 1040;
        int cell = rem >> 2;
        int q2 = rem & 3;
        int r, col;
        if (cell < 66)       { r = 0;  col = cell; }
        else if (cell < 132) { r = 65; col = cell - 66; }
        else                 { int c2 = cell - 132; r = 1 + (c2 >> 1); col = (c2 & 1) * 65; }
        xq[(((size_t)b2 * HP + r) * HP + col) * 4 + q2] = 0ull;
    }

    __shared__ float sb[CIN];
    sb[tid] = bias1[b * CIN + tid];
    __syncthreads();
    const float* xp = x + ((size_t)b * CIN + (size_t)q * 64) * (HH * WW) + (size_t)h * WW + w;
    const float* bb = &sb[q * 64];
    unsigned long long m = 0;
    #pragma unroll
    for (int c = 0; c < 64; ++c) {
        if (xp[(size_t)c * (HH * WW)] + bb[c] > 0.f) m |= 1ull << c;
    }
    xq[(((size_t)b * HP + h + 1) * HP + (w + 1)) * 4 + q] = m;
}

// 1024 blocks (b*64+h). 256 threads = 4 waves; lane = output channel.
// wave = (ohalf, whalf): o = ohalf*64+lane, pixels w = whalf*32+0..31.
// Weights (36 u64) resident in VGPRs; per-pixel xpack via wave-uniform
// scalar loads. Output transposed through LDS for coalesced epilogue.
__global__ __launch_bounds__(256, 4) void main_k(
    const unsigned long long* __restrict__ wpack,   // [128][9][4]
    const unsigned long long* __restrict__ xpack,   // [16][66][66][4]
    const int* __restrict__ ctab,                   // [128][8]
    const float* __restrict__ x,
    const float* __restrict__ A, const float* __restrict__ B0,
    const float* __restrict__ bias2, const float* __restrict__ bias3,
    const float* __restrict__ prelu_a,
    float* __restrict__ out)
{
    __shared__ float smem[COUT * 65];   // 33280 B
    int bid = blockIdx.x;
    int b = bid >> 6;
    int h = bid & 63;
    int tid = threadIdx.x;
    int lane = tid & 63;
    int wave = tid >> 6;
    int ohalf = wave >> 1;
    int whalf = wave & 1;
    int o = ohalf * 64 + lane;

    // resident per-lane weights (loop-invariant across the pixel loop)
    unsigned long long wl[36];
    {
        const unsigned long long* wp = wpack + (size_t)o * 36;
        #pragma unroll
        for (int j = 0; j < 36; ++j) wl[j] = wp[j];
    }
    const int* ct = ctab + o * 8;
    int ctT = ct[0], ctB = ct[1], ctL = ct[2], ctR = ct[3];
    int ctTL = ct[4], ctTR = ct[5], ctBL = ct[6], ctBR = ct[7];
    float Ao = A[o], B0o = B0[o];

    int hm = (h == 0) ? 1 : (h == 63) ? 2 : 0;   // block-uniform

    for (int i = 0; i < 32; ++i) {
        int wpix = __builtin_amdgcn_readfirstlane(whalf * 32 + i);  // uniform
        // tap (r,dw) reads padded (h+r, wpix+dw); row r starts at col wpix
        const unsigned long long* p0 =
            xpack + ((size_t)(b * HP + h) * HP + wpix) * 4;
        int P = 0;
        #pragma unroll
        for (int j = 0; j < 12; ++j) P += __popcll(p0[j] ^ wl[j]);
        #pragma unroll
        for (int j = 0; j < 12; ++j) P += __popcll(p0[4 * HP + j] ^ wl[12 + j]);
        #pragma unroll
        for (int j = 0; j < 12; ++j) P += __popcll(p0[8 * HP + j] ^ wl[24 + j]);

        // border correction (uniform branches; interior pixels skip all)
        int corr = 0, nvr = 3, nvc = 3;
        if (hm == 1) { corr += ctT; nvr = 2; }
        if (hm == 2) { corr += ctB; nvr = 2; }
        if (wpix == 0) {
            corr += ctL; nvc = 2;
            if (hm == 1) corr -= ctTL;
            if (hm == 2) corr -= ctBL;
        }
        if (wpix == 63) {
            corr += ctR; nvc = 2;
            if (hm == 1) corr -= ctTR;
            if (hm == 2) corr -= ctBR;
        }
        int nv = nvr * nvc;
        float cv = (float)(nv * 256 - 2 * (P - corr)) * Ao + B0o;
        smem[o * 65 + wpix] = cv;
    }
    __syncthreads();

    // coalesced writeback: residual + bias2 + PReLU + bias3
    #pragma unroll 4
    for (int i = 0; i < 32; ++i) {
        int idx = tid + i * 256;
        int oo = idx >> 6;       // wave-uniform per iteration
        int ww = idx & 63;
        float cv = smem[oo * 65 + ww];
        float r0 = x[(((size_t)b * CIN + 2 * oo) * HH + h) * WW + ww];
        float r1 = x[(((size_t)b * CIN + 2 * oo + 1) * HH + h) * WW + ww];
        float tv = cv + 0.5f * (r0 + r1) + bias2[b * COUT + oo];
        tv = tv > 0.f ? tv : prelu_a[oo] * tv;
        out[(((size_t)b * COUT + oo) * HH + h) * WW + ww] = tv + bias3[b * COUT + oo];
    }
}

extern "C" void kernel_launch(void* const* d_in, const int* in_sizes, int n_in,
                              void* d_out, int out_size, void* d_ws, size_t ws_size,
                              hipStream_t stream) {
    const float* x      = (const float*)d_in[0];
    const float* emb    = (const float*)d_in[1];
    const float* m1w    = (const float*)d_in[2];
    const float* m1b    = (const float*)d_in[3];
    const float* conv_w = (const float*)d_in[4];
    const float* conv_b = (const float*)d_in[5];
    const float* bn_g   = (const float*)d_in[6];
    const float* bn_b   = (const float*)d_in[7];
    const float* bn_m   = (const float*)d_in[8];
    const float* bn_v   = (const float*)d_in[9];
    const float* m2w    = (const float*)d_in[10];
    const float* m2b    = (const float*)d_in[11];
    const float* pa     = (const float*)d_in[12];
    const float* m3w    = (const float*)d_in[13];
    const float* m3b    = (const float*)d_in[14];
    float* out = (float*)d_out;

    char* ws = (char*)d_ws;
    float* bias1 = (float*)(ws + 0);
    float* bias2 = (float*)(ws + 16384);
    float* bias3 = (float*)(ws + 24576);
    float* Aarr  = (float*)(ws + 33280);
    float* B0arr = (float*)(ws + 33792);
    int*   ctab  = (int*)(ws + 34304);
    unsigned long long* wpack = (unsigned long long*)(ws + 38400);
    unsigned long long* xpack = (unsigned long long*)(ws + 75264);

    prep_k<<<256, 256, 0, stream>>>(emb, m1w, m1b, m2w, m2b, m3w, m3b,
                                    conv_w, conv_b, bn_g, bn_b, bn_m, bn_v,
                                    bias1, bias2, bias3, Aarr, B0arr, ctab, wpack);
    pack_k<<<BB * HH, 256, 0, stream>>>(x, bias1, xpack);
    main_k<<<BB * HH, 256, 0, stream>>>(wpack, xpack, ctab, x, Aarr, B0arr,
                                        bias2, bias3, pa, out);
}

// Round 9
// 69.519 us; speedup vs baseline: 1.7271x; 1.3559x over previous
//
#include <hip/hip_runtime.h>

#define BB 16
#define CIN 256
#define COUT 128
#define EE 512
#define HH 64
#define WW 64
#define HP 66   // padded spatial dim

// ws layout (bytes):
//   bias1 [16][256] f32 @ 0        (16384)
//   bias2 [16][128] f32 @ 16384    (8192)
//   bias3 [16][128] f32 @ 24576    (8192)
//   A     [128] f32     @ 33280    (512)
//   B0    [128] f32     @ 33792    (512)
//   ctab  [128][8] i32  @ 34304    (4096)   {T,B,L,R,TL,TR,BL,BR} popc sums
//   wq    [4][128][9] u64 @ 38400  (36864)  (quarter, o, tap)
//   xpack [16][66][66][4] u64 @ 75264 (2230272)  zero-padded halo

// grid: 128 bias-chunk blocks (b*8+chunk) + 128 weight blocks.
__global__ __launch_bounds__(256) void prep_k(
    const float* __restrict__ emb,
    const float* __restrict__ m1w, const float* __restrict__ m1b,
    const float* __restrict__ m2w, const float* __restrict__ m2b,
    const float* __restrict__ m3w, const float* __restrict__ m3b,
    const float* __restrict__ conv_w, const float* __restrict__ conv_b,
    const float* __restrict__ bn_g, const float* __restrict__ bn_b,
    const float* __restrict__ bn_m, const float* __restrict__ bn_v,
    float* __restrict__ bias1, float* __restrict__ bias2, float* __restrict__ bias3,
    float* __restrict__ A, float* __restrict__ B0,
    int* __restrict__ ctab, unsigned long long* __restrict__ wq)
{
    int bid = blockIdx.x;
    int tid = threadIdx.x;
    __shared__ float red[256];
    if (bid < 128) {
        // bias dot-products: b = bid>>3, chunk = bid&7
        int b = bid >> 3;
        int chunk = bid & 7;
        __shared__ float se[EE];
        {
            float v0 = emb[b * EE + tid];
            float v1 = emb[b * EE + tid + 256];
            se[tid] = v0 / (1.0f + __expf(-v0));
            se[tid + 256] = v1 / (1.0f + __expf(-v1));
        }
        __syncthreads();
        int cl = tid & 63;
        int ks = tid >> 6;   // 0..3, each covers 128 e's
        const float* W;
        const float* Bv;
        float* dst;
        int c0;
        if (chunk < 4)      { c0 = chunk * 64;       W = m1w; Bv = m1b; dst = bias1 + b * CIN + c0; }
        else if (chunk < 6) { c0 = (chunk - 4) * 64; W = m2w; Bv = m2b; dst = bias2 + b * COUT + c0; }
        else                { c0 = (chunk - 6) * 64; W = m3w; Bv = m3b; dst = bias3 + b * COUT + c0; }
        const float4* w4 = (const float4*)(W + (size_t)(c0 + cl) * EE + ks * 128);
        const float* sp = &se[ks * 128];
        float acc = 0.f;
        #pragma unroll
        for (int e4 = 0; e4 < 32; ++e4) {
            float4 v = w4[e4];
            acc += sp[e4 * 4 + 0] * v.x + sp[e4 * 4 + 1] * v.y +
                   sp[e4 * 4 + 2] * v.z + sp[e4 * 4 + 3] * v.w;
        }
        red[tid] = acc;
        __syncthreads();
        if (ks == 0)
            dst[cl] = red[cl] + red[cl + 64] + red[cl + 128] + red[cl + 192] + Bv[c0 + cl];
    } else {
        int o = bid - 128;     // output channel
        int i = tid;           // input channel 0..255
        __shared__ int spc[36];
        float wv[9];
        float asum = 0.f;
        const float* wp = conv_w + ((size_t)o * CIN + i) * 9;
        #pragma unroll
        for (int k = 0; k < 9; ++k) {
            float v = wp[k];
            wv[k] = v;
            asum += fabsf(v);
        }
        int wave = tid >> 6;
        #pragma unroll
        for (int k = 0; k < 9; ++k) {
            unsigned long long m = __ballot(wv[k] > 0.0f);
            if ((tid & 63) == 0) {
                wq[((size_t)wave * COUT + o) * 9 + k] = m;
                spc[k * 4 + wave] = __popcll(m);
            }
        }
        red[tid] = asum;
        __syncthreads();
        for (int s = 128; s > 0; s >>= 1) {
            if (tid < s) red[tid] += red[tid + s];
            __syncthreads();
        }
        if (tid < 9)
            spc[tid] = spc[tid * 4 + 0] + spc[tid * 4 + 1] + spc[tid * 4 + 2] + spc[tid * 4 + 3];
        __syncthreads();
        if (tid == 0) {
            float sc = red[0] * (1.0f / 2304.0f);
            float inv = bn_g[o] * rsqrtf(bn_v[o] + 1e-5f);
            A[o] = sc * inv;
            B0[o] = (conv_b[o] - bn_m[o]) * inv + bn_b[o];
            int p0 = spc[0], p1 = spc[1], p2 = spc[2];
            int p3 = spc[3], p5 = spc[5];
            int p6 = spc[6], p7 = spc[7], p8 = spc[8];
            int* ct = ctab + o * 8;
            ct[0] = p0 + p1 + p2;   // T (row r=0 invalid)
            ct[1] = p6 + p7 + p8;   // B (row r=2 invalid)
            ct[2] = p0 + p3 + p6;   // L (col dw=0 invalid)
            ct[3] = p2 + p5 + p8;   // R (col dw=2 invalid)
            ct[4] = p0;             // TL corner
            ct[5] = p2;             // TR
            ct[6] = p6;             // BL
            ct[7] = p8;             // BR
        }
    }
}

// One block per (b,h) row. 256 threads = 64 w-lanes x 4 channel-quarters.
// Writes padded xpack [16][66][66][4]; also zeroes the halo ring.
__global__ __launch_bounds__(256) void pack_k(
    const float* __restrict__ x, const float* __restrict__ bias1,
    unsigned long long* __restrict__ xq)
{
    int bid = blockIdx.x;          // b*64 + h
    int b = bid >> 6;
    int h = bid & 63;
    int tid = threadIdx.x;
    int w = tid & 63;
    int q = tid >> 6;              // channel quarter, wave-uniform

    // halo zeroing: 16 b * 260 ring-cells * 4 q = 16640 u64; 17 per block
    int idx = bid * 17 + tid;
    if (tid < 17 && idx < 16640) {
        int b2 = idx / 1040;
        int rem = idx % 1040;
        int cell = rem >> 2;
        int q2 = rem & 3;
        int r, col;
        if (cell < 66)       { r = 0;  col = cell; }
        else if (cell < 132) { r = 65; col = cell - 66; }
        else                 { int c2 = cell - 132; r = 1 + (c2 >> 1); col = (c2 & 1) * 65; }
        xq[(((size_t)b2 * HP + r) * HP + col) * 4 + q2] = 0ull;
    }

    __shared__ float sb[CIN];
    sb[tid] = bias1[b * CIN + tid];
    __syncthreads();
    const float* xp = x + ((size_t)b * CIN + (size_t)q * 64) * (HH * WW) + (size_t)h * WW + w;
    const float* bb = &sb[q * 64];
    unsigned long long m = 0;
    #pragma unroll
    for (int c = 0; c < 64; ++c) {
        if (xp[(size_t)c * (HH * WW)] + bb[c] > 0.f) m |= 1ull << c;
    }
    xq[(((size_t)b * HP + h + 1) * HP + (w + 1)) * 4 + q] = m;
}

// 1024 blocks (b*64+h). 512 threads = 8 waves = (oh in 2) x (q in 4).
// lane = o (within half); per-lane weights = 9 u64 (18 VGPRs, resident).
// x taps are wave-uniform scalar loads; partial P accumulated across the
// 4 q-waves via ds_add into Pacc[64][129] (conflict-free both phases).
__global__ __launch_bounds__(512, 4) void main_k(
    const unsigned long long* __restrict__ wq,      // [4][128][9]
    const unsigned long long* __restrict__ xpack,   // [16][66][66][4]
    const int* __restrict__ ctab,                   // [128][8]
    const float* __restrict__ x,
    const float* __restrict__ A, const float* __restrict__ B0,
    const float* __restrict__ bias2, const float* __restrict__ bias3,
    const float* __restrict__ prelu_a,
    float* __restrict__ out)
{
    __shared__ int Pacc[WW * (COUT + 1)];   // [64][129] = 33024 B
    int bid = blockIdx.x;
    int b = bid >> 6;
    int h = bid & 63;
    int tid = threadIdx.x;
    int lane = tid & 63;
    int wid = __builtin_amdgcn_readfirstlane(tid >> 6);  // 0..7
    int q = wid & 3;
    int oh = wid >> 2;
    int o = oh * 64 + lane;

    #pragma unroll
    for (int i = 0; i < 17; ++i) {
        int idx = tid + i * 512;
        if (idx < WW * (COUT + 1)) Pacc[idx] = 0;
    }

    // resident per-lane weights: 9 u64 for (q, o)
    unsigned long long wl[9];
    {
        const unsigned long long* wp = wq + ((size_t)q * COUT + o) * 9;
        #pragma unroll
        for (int t = 0; t < 9; ++t) wl[t] = wp[t];
    }
    __syncthreads();

    // wave-uniform x base: padded row h, quarter q
    const unsigned long long* xb =
        xpack + ((size_t)(b * HP + h) * HP) * 4 + q;

    #pragma unroll 4
    for (int w = 0; w < WW; ++w) {
        int P = 0;
        #pragma unroll
        for (int r = 0; r < 3; ++r) {
            #pragma unroll
            for (int dw = 0; dw < 3; ++dw) {
                unsigned long long xv = xb[(size_t)(r * HP + w + dw) * 4];
                P += __popcll(xv ^ wl[r * 3 + dw]);
            }
        }
        atomicAdd(&Pacc[w * (COUT + 1) + o], P);
    }
    __syncthreads();

    // epilogue: 16 outputs/thread, coalesced over w
    int hm = (h == 0) ? 1 : (h == 63) ? 2 : 0;   // block-uniform
    #pragma unroll
    for (int i = 0; i < 16; ++i) {
        int idx = i * 512 + tid;
        int o2 = __builtin_amdgcn_readfirstlane(idx >> 6);
        int w2 = idx & 63;
        int P = Pacc[w2 * (COUT + 1) + o2];
        const int* ct = ctab + o2 * 8;
        int corr = 0, nvr = 3;
        int ctLa = ct[2], ctRa = ct[3];
        if (hm == 1) { corr += ct[0]; nvr = 2; ctLa -= ct[4]; ctRa -= ct[5]; }
        if (hm == 2) { corr += ct[1]; nvr = 2; ctLa -= ct[6]; ctRa -= ct[7]; }
        int m0  = (w2 == 0)  ? -1 : 0;
        int m63 = (w2 == 63) ? -1 : 0;
        int nvc = 3 + m0 + m63;
        corr += (m0 & ctLa) + (m63 & ctRa);
        float cv = (float)(nvr * nvc * 256 - 2 * (P - corr)) * A[o2] + B0[o2];
        float r0 = x[((size_t)(b * CIN + 2 * o2) * HH + h) * WW + w2];
        float r1 = x[((size_t)(b * CIN + 2 * o2 + 1) * HH + h) * WW + w2];
        float tv = cv + 0.5f * (r0 + r1) + bias2[b * COUT + o2];
        tv = tv > 0.f ? tv : prelu_a[o2] * tv;
        out[((size_t)(b * COUT + o2) * HH + h) * WW + w2] = tv + bias3[b * COUT + o2];
    }
}

extern "C" void kernel_launch(void* const* d_in, const int* in_sizes, int n_in,
                              void* d_out, int out_size, void* d_ws, size_t ws_size,
                              hipStream_t stream) {
    const float* x      = (const float*)d_in[0];
    const float* emb    = (const float*)d_in[1];
    const float* m1w    = (const float*)d_in[2];
    const float* m1b    = (const float*)d_in[3];
    const float* conv_w = (const float*)d_in[4];
    const float* conv_b = (const float*)d_in[5];
    const float* bn_g   = (const float*)d_in[6];
    const float* bn_b   = (const float*)d_in[7];
    const float* bn_m   = (const float*)d_in[8];
    const float* bn_v   = (const float*)d_in[9];
    const float* m2w    = (const float*)d_in[10];
    const float* m2b    = (const float*)d_in[11];
    const float* pa     = (const float*)d_in[12];
    const float* m3w    = (const float*)d_in[13];
    const float* m3b    = (const float*)d_in[14];
    float* out = (float*)d_out;

    char* ws = (char*)d_ws;
    float* bias1 = (float*)(ws + 0);
    float* bias2 = (float*)(ws + 16384);
    float* bias3 = (float*)(ws + 24576);
    float* Aarr  = (float*)(ws + 33280);
    float* B0arr = (float*)(ws + 33792);
    int*   ctab  = (int*)(ws + 34304);
    unsigned long long* wq = (unsigned long long*)(ws + 38400);
    unsigned long long* xpack = (unsigned long long*)(ws + 75264);

    prep_k<<<256, 256, 0, stream>>>(emb, m1w, m1b, m2w, m2b, m3w, m3b,
                                    conv_w, conv_b, bn_g, bn_b, bn_m, bn_v,
                                    bias1, bias2, bias3, Aarr, B0arr, ctab, wq);
    pack_k<<<BB * HH, 256, 0, stream>>>(x, bias1, xpack);
    main_k<<<BB * HH, 512, 0, stream>>>(wq, xpack, ctab, x, Aarr, B0arr,
                                        bias2, bias3, pa, out);
}